// Round 9
// baseline (239.015 us; speedup 1.0000x reference)
//
#include <hip/hip_runtime.h>

// BertSelfAttention on MI355X: bf16 MFMA QKV GEMM + flash-style attention.
// B=8 S=1024 HID=1024 NH=16 HD=64.
// R15: fuse fp32->bf16 conversion into k_gemm A-staging (T14 async-split).
// Eliminates the hbf intermediate entirely: hidden read once (fp32) by gemm;
// k_prep shrinks to the 3072 W-transpose blocks. A-staging is reg-staged:
// float4 loads for tile kt+1 issue BEFORE compute(kt) (latency hides under
// 48 MFMAs), cvt (rne16, bit-identical to old prep) + swizzled ds_write_b128
// after compute, draining at the existing barrier. B keeps async16. Swizzle
// and read side untouched (R14-proven). Saves ~10us of conversion round-trip
// traffic + one kernel's work from the serial chain.
// k_attn identical to R13/R14. k_gemm geometry identical to R14
// (128x384, BK=32, 4 waves 64x192, 64KB LDS, grid 512 = 1 exact round).

typedef __bf16 bf16x8 __attribute__((ext_vector_type(8)));
typedef float f32x4 __attribute__((ext_vector_type(4)));
typedef float f32x16 __attribute__((ext_vector_type(16)));

__device__ __forceinline__ unsigned rne16(float x) {
  unsigned u = __builtin_bit_cast(unsigned, x);
  return (u + 0x7fffu + ((u >> 16) & 1u)) >> 16;
}
__device__ __forceinline__ unsigned packbf(float lo, float hi) {
  return rne16(lo) | (rne16(hi) << 16);
}
// fast pack (round-half-up) for softmax probabilities.
__device__ __forceinline__ unsigned packbf_fast(float lo, float hi) {
  unsigned ul = __builtin_bit_cast(unsigned, lo) + 0x8000u;
  unsigned uh = __builtin_bit_cast(unsigned, hi) + 0x8000u;
  return __builtin_amdgcn_perm(uh, ul, 0x07060302u);
}
// async global->LDS, 16B per lane; LDS dst is wave-uniform base + lane*16.
__device__ __forceinline__ void async16(void* l, const void* g) {
  __builtin_amdgcn_global_load_lds((const __attribute__((address_space(1))) void*)g,
                                   (__attribute__((address_space(3))) void*)l, 16, 0, 0);
}

// ---------------- W transpose only (3072 blocks) ----------------
__global__ __launch_bounds__(256) void k_prep(const float* __restrict__ Wq,
                                              const float* __restrict__ Wk,
                                              const float* __restrict__ Wv,
                                              unsigned short* __restrict__ wt) {
  __shared__ float t[32][33];
  int id = blockIdx.x, tid = threadIdx.x;  // 0..3071
  int which = id >> 10;
  int sub = id & 1023;
  int c0 = (sub & 31) * 32, k0 = (sub >> 5) * 32;
  const float* W = which == 0 ? Wq : (which == 1 ? Wk : Wv);
  int tx = tid & 31, ty = tid >> 5;
#pragma unroll
  for (int i = 0; i < 4; ++i) {
    int r = ty + i * 8;
    t[r][tx] = W[(size_t)(k0 + r) * 1024 + c0 + tx];
  }
  __syncthreads();
#pragma unroll
  for (int i = 0; i < 4; ++i) {
    int r = ty + i * 8;
    wt[((size_t)which * 1024 + c0 + r) * 1024 + k0 + tx] = (unsigned short)rne16(t[tx][r]);
  }
}

// ---------------- QKV GEMM: fp32 hidden [8192x1024] x wt[3072x1024]^T + bias ----------------
// 128x384 tile, BK=32, double-buffered 32KB: A [128][32] bf16 (8KB, 8 swizzled
// 1KB subtiles) at +0, B [384][32] (24KB) at +8192. A is REG-STAGED from fp32
// hidden: loads for kt+1 issue before compute(kt), cvt+swizzled ds_write after
// (drains at the barrier). B stays async16 with the inverse-swizzled source.
// 4 waves, wave tile 64x192 (16 ds_reads feed 48 MFMA per K-step). Grid
// 512 = 2 blocks/CU x 256 CU = one exact residency round.
__global__ __launch_bounds__(256, 2) void k_gemm(const float* __restrict__ h,
                                                 const unsigned short* __restrict__ Bm,
                                                 const float* __restrict__ bq,
                                                 const float* __restrict__ bk,
                                                 const float* __restrict__ bv,
                                                 unsigned short* __restrict__ qkv,
                                                 unsigned short* __restrict__ vt) {
  __shared__ __align__(16) char lds[65536];
  const int tid = threadIdx.x;
  const int w = tid >> 6, lane = tid & 63;
  const int wm = w >> 1, wn = w & 1;  // wave tile 64 rows x 192 cols

  // bijective XCD swizzle: 512 blocks = 8 XCDs x 64; tn fastest within a
  // chunk so each XCD's L2 holds 8 A-panels (4MB fp32) while B rotates.
  int orig = blockIdx.x;
  int wgid = (orig & 7) * 64 + (orig >> 3);
  int tm = wgid >> 3, tn = wgid & 7;
  int m0 = tm * 128, n0 = tn * 384;

  // staging map: linear LDS dest chunk o -> (row, k) source, inverse of the
  // read-side swizzle (same involution; proven R11/R14). Chunks of 16B map to
  // 8 consecutive k at row ro, col base ke (bit5 of the byte offset is
  // constant within a 16B chunk).
  int ro[6], ke[6];
#pragma unroll
  for (int j = 0; j < 6; ++j) {
    int o = j * 4096 + tid * 16;
    int s = o >> 10, w10 = o & 1023;
    int lg = w10 ^ (((w10 >> 9) & 1) << 5);
    ro[j] = s * 16 + (lg >> 6);
    ke[j] = (lg & 63) >> 1;
  }
  auto stageB = [&](int kt, char* buf) {
    const unsigned short* Bs = Bm + (size_t)n0 * 1024 + kt * 32;
#pragma unroll
    for (int j = 0; j < 6; ++j)
      async16(buf + 8192 + j * 4096 + tid * 16, Bs + (size_t)ro[j] * 1024 + ke[j]);
  };
  // A reg-staging: load fp32 (issue early), cvt+write late.
  float4 aU[2], aV[2];
  auto loadA = [&](int kt) {
    const float* As = h + (size_t)m0 * 1024 + kt * 32;
#pragma unroll
    for (int j = 0; j < 2; ++j) {
      const float* p = As + (size_t)ro[j] * 1024 + ke[j];
      aU[j] = *(const float4*)(p);
      aV[j] = *(const float4*)(p + 4);
    }
  };
  auto writeA = [&](char* buf) {
#pragma unroll
    for (int j = 0; j < 2; ++j) {
      uint4 pk;
      pk.x = packbf(aU[j].x, aU[j].y);
      pk.y = packbf(aU[j].z, aU[j].w);
      pk.z = packbf(aV[j].x, aV[j].y);
      pk.w = packbf(aV[j].z, aV[j].w);
      *(uint4*)(buf + j * 4096 + tid * 16) = pk;
    }
  };

  // read-side per-lane swizzled offset within a 1KB subtile.
  const int lswz = (((lane & 15) << 6) | ((lane >> 4) << 4)) ^ ((lane & 8) << 2);

  f32x4 acc[4][12];
#pragma unroll
  for (int i = 0; i < 4; ++i)
#pragma unroll
    for (int j = 0; j < 12; ++j)
#pragma unroll
      for (int e = 0; e < 4; ++e) acc[i][j][e] = 0.f;

  auto compute = [&](const char* buf) {
    const char* abase = buf + lswz;
    const char* bbase = buf + 8192 + lswz;
    bf16x8 aF[4];
#pragma unroll
    for (int mt = 0; mt < 4; ++mt)
      aF[mt] = *(const bf16x8*)(abase + ((size_t)(wm * 4 + mt) << 10));
#pragma unroll
    for (int n = 0; n < 12; ++n) {
      bf16x8 bF = *(const bf16x8*)(bbase + ((size_t)(wn * 12 + n) << 10));
#pragma unroll
      for (int mt = 0; mt < 4; ++mt)
        acc[mt][n] =
            __builtin_amdgcn_mfma_f32_16x16x32_bf16(aF[mt], bF, acc[mt][n], 0, 0, 0);
    }
  };

  char* buf0 = lds;
  char* buf1 = lds + 32768;
  loadA(0);
  stageB(0, buf0);
  writeA(buf0);
#pragma unroll 1
  for (int kt = 0; kt < 32; kt += 2) {
    __syncthreads();  // buf0 ready (A writes + B async drained)
    loadA(kt + 1);    // issue fp32 loads early; latency hides under compute
    stageB(kt + 1, buf1);
    compute(buf0);
    writeA(buf1);     // cvt + swizzled ds_write; drains at next barrier
    __syncthreads();
    if (kt + 2 < 32) {
      loadA(kt + 2);
      stageB(kt + 2, buf0);
    }
    compute(buf1);
    if (kt + 2 < 32) writeA(buf0);
  }

  // epilogue. C fragment: col(n) = lane&15, row(s) = (lane>>4)*4 + e.
  // which is per-n-frag (wave-uniform: frags are 16-wide, boundaries 1024).
  const int b = m0 >> 10;
  const int r = lane & 15, qq = lane >> 4;
  const int sb = (m0 & 1023) + wm * 64 + qq * 4;
#pragma unroll
  for (int n = 0; n < 12; ++n) {
    int n_gf = n0 + wn * 192 + n * 16;
    int which = n_gf >> 10;
    int n_in = (n_gf & 1023) + r;
    if (which != 2) {
      // q / k: scattered 2B stores into [b][h][s][d] (proven path).
      const float* bp = which == 0 ? bq : bk;
      float bias = bp[n_in];
      unsigned short* dp = qkv + ((size_t)which << 23) + ((size_t)b << 20) +
                           ((size_t)(n_in >> 6) << 16) + (n_in & 63);
#pragma unroll
      for (int m = 0; m < 4; ++m)
#pragma unroll
        for (int e = 0; e < 4; ++e)
          dp[(size_t)(sb + m * 16 + e) << 6] = (unsigned short)rne16(acc[m][n][e] + bias);
    } else {
      // v: store V^T [b][h][d][s] directly — each lane owns 4 consecutive s
      // (e=0..3) at fixed d, packed as one 8B store.
      float bias = bv[n_in];
      unsigned short* dp = vt + ((size_t)b << 20) + ((size_t)n_in << 10) + sb;
#pragma unroll
      for (int m = 0; m < 4; ++m) {
        uint2 pk;
        pk.x = packbf(acc[m][n][0] + bias, acc[m][n][1] + bias);
        pk.y = packbf(acc[m][n][2] + bias, acc[m][n][3] + bias);
        *(uint2*)(dp + m * 16) = pk;
      }
    }
  }
}

// ---------------- attention: S^T = K*Q^T, softmax (no max-sub), O^T = V^T*P ----------------
// 512 blocks; block = (b,h, 256-qrow chunk); wave = 64 qrows (two 32-row Q
// fragments qh=0,1 SHARING each K/V LDS read). 64-key tiles, double-buffered
// K/V staging, one barrier per kt. XCD swizzle: b = blockIdx&7. 2 blocks/CU.
__global__ __launch_bounds__(256, 2) void k_attn(const unsigned short* __restrict__ qg,
                                                 const unsigned short* __restrict__ kg,
                                                 const unsigned short* __restrict__ vtg,
                                                 const float* __restrict__ maskg,
                                                 float* __restrict__ out) {
  __shared__ __align__(16) char lds[36864];
  // buffers d=0,1 at d*16384: K 8KB (64 keys x 64 dims) + V^T 8KB (64 dims x
  // 64 keys). Mask table 4KB at +32768. Epilogue scratch reuses buffers.
  float* MK = (float*)(lds + 32768);
  int tid = threadIdx.x, w = tid >> 6, lane = tid & 63, l5 = lane & 31, q5 = lane >> 5;
  int idx = blockIdx.x;
  int bi = idx & 7;                   // batch == XCD (round-robin dispatch heuristic)
  int j = idx >> 3;                   // 0..63
  int h = j >> 2, qc = j & 3;
  int bh = bi * 16 + h, s0 = qc * 256;
  const unsigned short* qb = qg + ((size_t)bh << 16);
  const unsigned short* kb = kg + ((size_t)bh << 16);
  const unsigned short* vb = vtg + ((size_t)bh << 16);
  const float LG = 1.4426950408889634f;
  const float C1 = 0.125f * LG;

  {
    float4 mv = *(const float4*)(maskg + (size_t)bi * 1024 + tid * 4);
    mv.x *= LG; mv.y *= LG; mv.z *= LG; mv.w *= LG;
    *(float4*)(MK + tid * 4) = mv;
  }

  // stage K/V tile kt (64 keys at k0=kt*64) into buffer buf. Per wave: 2 K
  // chunks + 2 V chunks (4 waves cover 8+8 x 1KB). Per-lane identity
  // correspondence between write and read (harness-verified map).
  auto stageKV = [&](int kt, char* buf) {
    int k0 = kt * 64;
#pragma unroll
    for (int t = 0; t < 2; ++t) {
      int f = w * 2 + t;
      int mt = f >> 2, ds = f & 3;
      async16(buf + f * 1024, kb + (size_t)(k0 + mt * 32 + l5) * 64 + ds * 16 + q5 * 8);
      int dt = f >> 2, ks = f & 3;
      async16(buf + 8192 + f * 1024,
              vb + (size_t)(dt * 32 + l5) * 1024 + k0 + ks * 16 + q5 * 8);
    }
  };

  bf16x8 qfr[2][4];
#pragma unroll
  for (int qh = 0; qh < 2; ++qh)
#pragma unroll
    for (int ds = 0; ds < 4; ++ds)
      qfr[qh][ds] = *(const bf16x8*)(qb + (size_t)(s0 + w * 64 + qh * 32 + l5) * 64 +
                                     ds * 16 + q5 * 8);

  f32x16 O[2][2];
#pragma unroll
  for (int qh = 0; qh < 2; ++qh)
#pragma unroll
    for (int i = 0; i < 2; ++i)
#pragma unroll
      for (int e = 0; e < 16; ++e) O[qh][i][e] = 0.f;
  float lsum0 = 0.f, lsum1 = 0.f;

  stageKV(0, lds);
  __syncthreads();  // tile 0 landed (implicit vmcnt(0)), mask table visible

#pragma unroll 1
  for (int kt = 0; kt < 16; ++kt) {
    char* buf = lds + (kt & 1) * 16384;
    if (kt < 15) stageKV(kt + 1, lds + ((kt + 1) & 1) * 16384);
    int k0 = kt * 64;
    const char* KF = buf;
    const char* VF = buf + 8192;
#pragma unroll
    for (int mt = 0; mt < 2; ++mt) {
      f32x16 S0, S1;
#pragma unroll
      for (int e = 0; e < 16; ++e) { S0[e] = 0.f; S1[e] = 0.f; }
#pragma unroll
      for (int ds = 0; ds < 4; ++ds) {
        bf16x8 a = *(const bf16x8*)(KF + (mt * 4 + ds) * 1024 + lane * 16);
        S0 = __builtin_amdgcn_mfma_f32_32x32x16_bf16(a, qfr[0][ds], S0, 0, 0, 0);
        S1 = __builtin_amdgcn_mfma_f32_32x32x16_bf16(a, qfr[1][ds], S1, 0, 0, 0);
      }
      unsigned p2a[8], p2b[8];
      {
        float p[16];
#pragma unroll
        for (int g4 = 0; g4 < 4; ++g4) {
          float4 mv = *(const float4*)(MK + k0 + mt * 32 + g4 * 8 + q5 * 4);
          p[g4 * 4 + 0] = __builtin_amdgcn_exp2f(S0[g4 * 4 + 0] * C1 + mv.x);
          p[g4 * 4 + 1] = __builtin_amdgcn_exp2f(S0[g4 * 4 + 1] * C1 + mv.y);
          p[g4 * 4 + 2] = __builtin_amdgcn_exp2f(S0[g4 * 4 + 2] * C1 + mv.z);
          p[g4 * 4 + 3] = __builtin_amdgcn_exp2f(S0[g4 * 4 + 3] * C1 + mv.w);
        }
#pragma unroll
        for (int e = 0; e < 16; ++e) lsum0 += p[e];
#pragma unroll
        for (int jj = 0; jj < 8; ++jj) p2a[jj] = packbf_fast(p[2 * jj], p[2 * jj + 1]);
      }
      {
        float p[16];
#pragma unroll
        for (int g4 = 0; g4 < 4; ++g4) {
          float4 mv = *(const float4*)(MK + k0 + mt * 32 + g4 * 8 + q5 * 4);
          p[g4 * 4 + 0] = __builtin_amdgcn_exp2f(S1[g4 * 4 + 0] * C1 + mv.x);
          p[g4 * 4 + 1] = __builtin_amdgcn_exp2f(S1[g4 * 4 + 1] * C1 + mv.y);
          p[g4 * 4 + 2] = __builtin_amdgcn_exp2f(S1[g4 * 4 + 2] * C1 + mv.z);
          p[g4 * 4 + 3] = __builtin_amdgcn_exp2f(S1[g4 * 4 + 3] * C1 + mv.w);
        }
#pragma unroll
        for (int e = 0; e < 16; ++e) lsum1 += p[e];
#pragma unroll
        for (int jj = 0; jj < 8; ++jj) p2b[jj] = packbf_fast(p[2 * jj], p[2 * jj + 1]);
      }
#pragma unroll
      for (int kh = 0; kh < 2; ++kh) {
        int ks = mt * 2 + kh, gp = kh * 4;
        bf16x8 av0 = *(const bf16x8*)(VF + (0 * 4 + ks) * 1024 + lane * 16);
        bf16x8 av1 = *(const bf16x8*)(VF + (1 * 4 + ks) * 1024 + lane * 16);
        {
          unsigned o0 = p2a[gp + 0], o1 = p2a[gp + 1];
          unsigned o2 = p2a[gp + 2], o3 = p2a[gp + 3];
          unsigned t0 = __shfl_xor((int)o0, 32);
          unsigned t1 = __shfl_xor((int)o1, 32);
          unsigned t2 = __shfl_xor((int)o2, 32);
          unsigned t3 = __shfl_xor((int)o3, 32);
          uint4 fu;
          fu.x = q5 ? t2 : o0;
          fu.y = q5 ? t3 : o1;
          fu.z = q5 ? o2 : t0;
          fu.w = q5 ? o3 : t1;
          bf16x8 bfrag = __builtin_bit_cast(bf16x8, fu);
          O[0][0] = __builtin_amdgcn_mfma_f32_32x32x16_bf16(av0, bfrag, O[0][0], 0, 0, 0);
          O[0][1] = __builtin_amdgcn_mfma_f32_32x32x16_bf16(av1, bfrag, O[0][1], 0, 0, 0);
        }
        {
          unsigned o0 = p2b[gp + 0], o1 = p2b[gp + 1];
          unsigned o2 = p2b[gp + 2], o3 = p2b[gp + 3];
          unsigned t0 = __shfl_xor((int)o0, 32);
          unsigned t1 = __shfl_xor((int)o1, 32);
          unsigned t2 = __shfl_xor((int)o2, 32);
          unsigned t3 = __shfl_xor((int)o3, 32);
          uint4 fu;
          fu.x = q5 ? t2 : o0;
          fu.y = q5 ? t3 : o1;
          fu.z = q5 ? o2 : t0;
          fu.w = q5 ? o3 : t1;
          bf16x8 bfrag = __builtin_bit_cast(bf16x8, fu);
          O[1][0] = __builtin_amdgcn_mfma_f32_32x32x16_bf16(av0, bfrag, O[1][0], 0, 0, 0);
          O[1][1] = __builtin_amdgcn_mfma_f32_32x32x16_bf16(av1, bfrag, O[1][1], 0, 0, 0);
        }
      }
    }
    __syncthreads();  // drains kt+1 staging (overlapped by compute above)
  }

  // epilogue: normalize, transpose O^T via wave-private swizzled LDS scratch
  // (buffers free after the final barrier); two sequential passes (qh=0,1)
  // reuse the same 8KB scratch -- within-wave DS ordering is guaranteed.
  float* Ob = (float*)(lds + w * 8192);
  float lt0 = lsum0 + __shfl_xor(lsum0, 32);
  float lt1 = lsum1 + __shfl_xor(lsum1, 32);
  float rinv0 = 1.0f / lt0;
  float rinv1 = 1.0f / lt1;
#pragma unroll
  for (int qh = 0; qh < 2; ++qh) {
    float rinv = qh ? rinv1 : rinv0;
#pragma unroll
    for (int dt = 0; dt < 2; ++dt)
#pragma unroll
      for (int g4 = 0; g4 < 4; ++g4) {
        float4 val;
        val.x = O[qh][dt][g4 * 4 + 0] * rinv;
        val.y = O[qh][dt][g4 * 4 + 1] * rinv;
        val.z = O[qh][dt][g4 * 4 + 2] * rinv;
        val.w = O[qh][dt][g4 * 4 + 3] * rinv;
        int c = dt * 8 + g4 * 2 + q5;
        *(float4*)(Ob + l5 * 64 + (c ^ (l5 & 15)) * 4) = val;
      }
#pragma unroll
    for (int t = 0; t < 8; ++t) {
      int qr = t * 4 + (lane >> 4), cr = lane & 15;
      float4 vv = *(const float4*)(Ob + qr * 64 + (cr ^ (qr & 15)) * 4);
      int s = s0 + w * 64 + qh * 32 + qr;
      *(float4*)(out + (((size_t)(bi * 1024 + s)) << 10) + (h << 6) + (cr << 2)) = vv;
    }
  }
}

extern "C" void kernel_launch(void* const* d_in, const int* in_sizes, int n_in,
                              void* d_out, int out_size, void* d_ws, size_t ws_size,
                              hipStream_t stream) {
  (void)in_sizes; (void)n_in; (void)out_size; (void)ws_size;
  const float* hidden = (const float*)d_in[0];
  const float* mask = (const float*)d_in[1];
  const float* Wq = (const float*)d_in[2];
  const float* bq = (const float*)d_in[3];
  const float* Wk = (const float*)d_in[4];
  const float* bk = (const float*)d_in[5];
  const float* Wv = (const float*)d_in[6];
  const float* bv = (const float*)d_in[7];
  float* out = (float*)d_out;
  char* ws = (char*)d_ws;
  unsigned short* wt  = (unsigned short*)(ws + 16777216);     //  6,291,456 B
  unsigned short* qkv = (unsigned short*)(ws + 23068672);     // 33,554,432 B (q,k)
  unsigned short* vt  = (unsigned short*)(ws + 56623104);     // 16,777,216 B (v^T)

  k_prep<<<3072, 256, 0, stream>>>(Wq, Wk, Wv, wt);
  k_gemm<<<512, 256, 0, stream>>>(hidden, wt, bq, bk, bv, qkv, vt);
  k_attn<<<512, 256, 0, stream>>>(qkv, qkv + 8388608, vt, mask, out);
}

// Round 10
// 217.529 us; speedup vs baseline: 1.0988x; 1.0988x over previous
//
#include <hip/hip_runtime.h>

// BertSelfAttention on MI355X: bf16 MFMA QKV GEMM + flash-style attention.
// B=8 S=1024 HID=1024 NH=16 HD=64.
// R16: revert R15's A-fusion (reg-staged cvt in the K-loop -> gemm ~100us,
// MfmaUtil 9-21%; un-hidden VALU+LDS-write on the critical path). Restore
// R14 prep/gemm split, then test the last untested occupancy point with the
// fat-wave structure: 128x256 tile, BK=32, 48KB LDS -> 3 blocks/CU (m97's
// proven geometry class, 874-912 TF via m114 cross-block overlap). Grid
// 64x12 = 768 = exactly one residency round (256 CU x 3). Wave tile 64x128
// (acc 4x8 f32x4; 12 ds_reads feed 32 MFMA = 2.67 MFMA/read). All components
// harness-proven: BK=32 swizzle maps (R11/R14), 2-barrier compiler-scheduled
// loop, epilogues (which = tn>>2, frag-aligned boundaries).
// k_prep / k_attn identical to R14 (= R13).

typedef __bf16 bf16x8 __attribute__((ext_vector_type(8)));
typedef float f32x4 __attribute__((ext_vector_type(4)));
typedef float f32x16 __attribute__((ext_vector_type(16)));

__device__ __forceinline__ unsigned rne16(float x) {
  unsigned u = __builtin_bit_cast(unsigned, x);
  return (u + 0x7fffu + ((u >> 16) & 1u)) >> 16;
}
__device__ __forceinline__ unsigned packbf(float lo, float hi) {
  return rne16(lo) | (rne16(hi) << 16);
}
// fast pack (round-half-up) for softmax probabilities.
__device__ __forceinline__ unsigned packbf_fast(float lo, float hi) {
  unsigned ul = __builtin_bit_cast(unsigned, lo) + 0x8000u;
  unsigned uh = __builtin_bit_cast(unsigned, hi) + 0x8000u;
  return __builtin_amdgcn_perm(uh, ul, 0x07060302u);
}
// async global->LDS, 16B per lane; LDS dst is wave-uniform base + lane*16.
__device__ __forceinline__ void async16(void* l, const void* g) {
  __builtin_amdgcn_global_load_lds((const __attribute__((address_space(1))) void*)g,
                                   (__attribute__((address_space(3))) void*)l, 16, 0, 0);
}

// ---------------- fused: hidden fp32->bf16 (blocks 0..8191) + W transpose (8192..11263) ----
__global__ __launch_bounds__(256) void k_prep(const float* __restrict__ h,
                                              unsigned short* __restrict__ hbf,
                                              const float* __restrict__ Wq,
                                              const float* __restrict__ Wk,
                                              const float* __restrict__ Wv,
                                              unsigned short* __restrict__ wt) {
  __shared__ float t[32][33];
  int bid = blockIdx.x, tid = threadIdx.x;
  if (bid < 8192) {
    size_t i = (size_t)bid * 256 + tid;
    float4 v = ((const float4*)h)[i];
    uint2 r;
    r.x = packbf(v.x, v.y);
    r.y = packbf(v.z, v.w);
    ((uint2*)hbf)[i] = r;
  } else {
    int id = bid - 8192;           // 0..3071
    int which = id >> 10;
    int sub = id & 1023;
    int c0 = (sub & 31) * 32, k0 = (sub >> 5) * 32;
    const float* W = which == 0 ? Wq : (which == 1 ? Wk : Wv);
    int tx = tid & 31, ty = tid >> 5;
#pragma unroll
    for (int i = 0; i < 4; ++i) {
      int r = ty + i * 8;
      t[r][tx] = W[(size_t)(k0 + r) * 1024 + c0 + tx];
    }
    __syncthreads();
#pragma unroll
    for (int i = 0; i < 4; ++i) {
      int r = ty + i * 8;
      wt[((size_t)which * 1024 + c0 + r) * 1024 + k0 + tx] = (unsigned short)rne16(t[tx][r]);
    }
  }
}

// ---------------- QKV GEMM: [8192x1024] x [1024x3072]^T + bias, 128x256 tile, BK=32 ----------
// Double-buffered LDS, 24KB per buffer: A [128][32] (8KB, 8 swizzled 1KB
// subtiles) at +0, B [256][32] (16KB, 16 subtiles) at +8192. Within each 1KB
// subtile byte offsets are XOR-swizzled (off ^= ((off>>9)&1)<<5); staging
// uses the inverse-swizzled global source, reads the swizzled lane offset ->
// conflict-free ds_read_b128 (maps proven R11/R14). 4 waves, wave grid
// 2m x 2n, wave tile 64x128: 12 ds_reads feed 32 MFMA per K-step. 48KB LDS
// -> 3 blocks/CU; grid 768 = one exact residency round; intra-block stalls
// overlap with 2 co-resident blocks' MFMA streams (m114/m97 mechanism).
__global__ __launch_bounds__(256, 3) void k_gemm(const unsigned short* __restrict__ A,
                                                 const unsigned short* __restrict__ Bm,
                                                 const float* __restrict__ bq,
                                                 const float* __restrict__ bk,
                                                 const float* __restrict__ bv,
                                                 unsigned short* __restrict__ qkv,
                                                 unsigned short* __restrict__ vt) {
  __shared__ __align__(16) char lds[49152];
  const int tid = threadIdx.x;
  const int w = tid >> 6, lane = tid & 63;
  const int wm = w >> 1, wn = w & 1;  // wave tile 64 rows x 128 cols

  // bijective XCD swizzle: 768 blocks = 8 XCDs x 96; tn fastest within a
  // chunk so each XCD's L2 keeps A-panels hot while B rotates.
  int orig = blockIdx.x;
  int wgid = (orig & 7) * 96 + (orig >> 3);
  int tm = wgid / 12, tn = wgid - tm * 12;
  int m0 = tm * 128, n0 = tn * 256;

  // staging map: linear LDS dest chunk o -> (row, k) source, inverse of the
  // read-side swizzle (same involution; proven R11/R14).
  int ro[4], ke[4];
#pragma unroll
  for (int j = 0; j < 4; ++j) {
    int o = j * 4096 + tid * 16;
    int s = o >> 10, w10 = o & 1023;
    int lg = w10 ^ (((w10 >> 9) & 1) << 5);
    ro[j] = s * 16 + (lg >> 6);
    ke[j] = (lg & 63) >> 1;
  }
  auto stage = [&](int kt, char* buf) {
    const unsigned short* As = A + (size_t)m0 * 1024 + kt * 32;
    const unsigned short* Bs = Bm + (size_t)n0 * 1024 + kt * 32;
#pragma unroll
    for (int j = 0; j < 2; ++j)
      async16(buf + j * 4096 + tid * 16, As + (size_t)ro[j] * 1024 + ke[j]);
#pragma unroll
    for (int j = 0; j < 4; ++j)
      async16(buf + 8192 + j * 4096 + tid * 16, Bs + (size_t)ro[j] * 1024 + ke[j]);
  };

  // read-side per-lane swizzled offset within a 1KB subtile.
  const int lswz = (((lane & 15) << 6) | ((lane >> 4) << 4)) ^ ((lane & 8) << 2);

  f32x4 acc[4][8];
#pragma unroll
  for (int i = 0; i < 4; ++i)
#pragma unroll
    for (int j = 0; j < 8; ++j)
#pragma unroll
      for (int e = 0; e < 4; ++e) acc[i][j][e] = 0.f;

  auto compute = [&](const char* buf) {
    const char* abase = buf + lswz;
    const char* bbase = buf + 8192 + lswz;
    bf16x8 aF[4];
#pragma unroll
    for (int mt = 0; mt < 4; ++mt)
      aF[mt] = *(const bf16x8*)(abase + ((size_t)(wm * 4 + mt) << 10));
#pragma unroll
    for (int n = 0; n < 8; ++n) {
      bf16x8 bF = *(const bf16x8*)(bbase + ((size_t)(wn * 8 + n) << 10));
#pragma unroll
      for (int mt = 0; mt < 4; ++mt)
        acc[mt][n] =
            __builtin_amdgcn_mfma_f32_16x16x32_bf16(aF[mt], bF, acc[mt][n], 0, 0, 0);
    }
  };

  char* buf0 = lds;
  char* buf1 = lds + 24576;
  stage(0, buf0);
#pragma unroll 1
  for (int kt = 0; kt < 32; kt += 2) {
    __syncthreads();
    stage(kt + 1, buf1);
    compute(buf0);
    __syncthreads();
    if (kt + 2 < 32) stage(kt + 2, buf0);
    compute(buf1);
  }

  // epilogue. C fragment: col(n) = lane&15, row(s) = (lane>>4)*4 + e.
  // which is per-n-frag (wave-uniform: frags are 16-wide, boundaries 1024).
  const int b = m0 >> 10;
  const int r = lane & 15, qq = lane >> 4;
  const int sb = (m0 & 1023) + wm * 64 + qq * 4;
#pragma unroll
  for (int n = 0; n < 8; ++n) {
    int n_gf = n0 + wn * 128 + n * 16;
    int which = n_gf >> 10;
    int n_in = (n_gf & 1023) + r;
    if (which != 2) {
      // q / k: scattered 2B stores into [b][h][s][d] (proven path).
      const float* bp = which == 0 ? bq : bk;
      float bias = bp[n_in];
      unsigned short* dp = qkv + ((size_t)which << 23) + ((size_t)b << 20) +
                           ((size_t)(n_in >> 6) << 16) + (n_in & 63);
#pragma unroll
      for (int m = 0; m < 4; ++m)
#pragma unroll
        for (int e = 0; e < 4; ++e)
          dp[(size_t)(sb + m * 16 + e) << 6] = (unsigned short)rne16(acc[m][n][e] + bias);
    } else {
      // v: store V^T [b][h][d][s] directly — each lane owns 4 consecutive s
      // (e=0..3) at fixed d, packed as one 8B store.
      float bias = bv[n_in];
      unsigned short* dp = vt + ((size_t)b << 20) + ((size_t)n_in << 10) + sb;
#pragma unroll
      for (int m = 0; m < 4; ++m) {
        uint2 pk;
        pk.x = packbf(acc[m][n][0] + bias, acc[m][n][1] + bias);
        pk.y = packbf(acc[m][n][2] + bias, acc[m][n][3] + bias);
        *(uint2*)(dp + m * 16) = pk;
      }
    }
  }
}

// ---------------- attention: S^T = K*Q^T, softmax (no max-sub), O^T = V^T*P ----------------
// 512 blocks; block = (b,h, 256-qrow chunk); wave = 64 qrows (two 32-row Q
// fragments qh=0,1 SHARING each K/V LDS read). 64-key tiles, double-buffered
// K/V staging, one barrier per kt. XCD swizzle: b = blockIdx&7. 2 blocks/CU.
__global__ __launch_bounds__(256, 2) void k_attn(const unsigned short* __restrict__ qg,
                                                 const unsigned short* __restrict__ kg,
                                                 const unsigned short* __restrict__ vtg,
                                                 const float* __restrict__ maskg,
                                                 float* __restrict__ out) {
  __shared__ __align__(16) char lds[36864];
  // buffers d=0,1 at d*16384: K 8KB (64 keys x 64 dims) + V^T 8KB (64 dims x
  // 64 keys). Mask table 4KB at +32768. Epilogue scratch reuses buffers.
  float* MK = (float*)(lds + 32768);
  int tid = threadIdx.x, w = tid >> 6, lane = tid & 63, l5 = lane & 31, q5 = lane >> 5;
  int idx = blockIdx.x;
  int bi = idx & 7;                   // batch == XCD (round-robin dispatch heuristic)
  int j = idx >> 3;                   // 0..63
  int h = j >> 2, qc = j & 3;
  int bh = bi * 16 + h, s0 = qc * 256;
  const unsigned short* qb = qg + ((size_t)bh << 16);
  const unsigned short* kb = kg + ((size_t)bh << 16);
  const unsigned short* vb = vtg + ((size_t)bh << 16);
  const float LG = 1.4426950408889634f;
  const float C1 = 0.125f * LG;

  {
    float4 mv = *(const float4*)(maskg + (size_t)bi * 1024 + tid * 4);
    mv.x *= LG; mv.y *= LG; mv.z *= LG; mv.w *= LG;
    *(float4*)(MK + tid * 4) = mv;
  }

  // stage K/V tile kt (64 keys at k0=kt*64) into buffer buf. Per wave: 2 K
  // chunks + 2 V chunks (4 waves cover 8+8 x 1KB). Per-lane identity
  // correspondence between write and read (harness-verified map).
  auto stageKV = [&](int kt, char* buf) {
    int k0 = kt * 64;
#pragma unroll
    for (int t = 0; t < 2; ++t) {
      int f = w * 2 + t;
      int mt = f >> 2, ds = f & 3;
      async16(buf + f * 1024, kb + (size_t)(k0 + mt * 32 + l5) * 64 + ds * 16 + q5 * 8);
      int dt = f >> 2, ks = f & 3;
      async16(buf + 8192 + f * 1024,
              vb + (size_t)(dt * 32 + l5) * 1024 + k0 + ks * 16 + q5 * 8);
    }
  };

  bf16x8 qfr[2][4];
#pragma unroll
  for (int qh = 0; qh < 2; ++qh)
#pragma unroll
    for (int ds = 0; ds < 4; ++ds)
      qfr[qh][ds] = *(const bf16x8*)(qb + (size_t)(s0 + w * 64 + qh * 32 + l5) * 64 +
                                     ds * 16 + q5 * 8);

  f32x16 O[2][2];
#pragma unroll
  for (int qh = 0; qh < 2; ++qh)
#pragma unroll
    for (int i = 0; i < 2; ++i)
#pragma unroll
      for (int e = 0; e < 16; ++e) O[qh][i][e] = 0.f;
  float lsum0 = 0.f, lsum1 = 0.f;

  stageKV(0, lds);
  __syncthreads();  // tile 0 landed (implicit vmcnt(0)), mask table visible

#pragma unroll 1
  for (int kt = 0; kt < 16; ++kt) {
    char* buf = lds + (kt & 1) * 16384;
    if (kt < 15) stageKV(kt + 1, lds + ((kt + 1) & 1) * 16384);
    int k0 = kt * 64;
    const char* KF = buf;
    const char* VF = buf + 8192;
#pragma unroll
    for (int mt = 0; mt < 2; ++mt) {
      f32x16 S0, S1;
#pragma unroll
      for (int e = 0; e < 16; ++e) { S0[e] = 0.f; S1[e] = 0.f; }
#pragma unroll
      for (int ds = 0; ds < 4; ++ds) {
        bf16x8 a = *(const bf16x8*)(KF + (mt * 4 + ds) * 1024 + lane * 16);
        S0 = __builtin_amdgcn_mfma_f32_32x32x16_bf16(a, qfr[0][ds], S0, 0, 0, 0);
        S1 = __builtin_amdgcn_mfma_f32_32x32x16_bf16(a, qfr[1][ds], S1, 0, 0, 0);
      }
      unsigned p2a[8], p2b[8];
      {
        float p[16];
#pragma unroll
        for (int g4 = 0; g4 < 4; ++g4) {
          float4 mv = *(const float4*)(MK + k0 + mt * 32 + g4 * 8 + q5 * 4);
          p[g4 * 4 + 0] = __builtin_amdgcn_exp2f(S0[g4 * 4 + 0] * C1 + mv.x);
          p[g4 * 4 + 1] = __builtin_amdgcn_exp2f(S0[g4 * 4 + 1] * C1 + mv.y);
          p[g4 * 4 + 2] = __builtin_amdgcn_exp2f(S0[g4 * 4 + 2] * C1 + mv.z);
          p[g4 * 4 + 3] = __builtin_amdgcn_exp2f(S0[g4 * 4 + 3] * C1 + mv.w);
        }
#pragma unroll
        for (int e = 0; e < 16; ++e) lsum0 += p[e];
#pragma unroll
        for (int jj = 0; jj < 8; ++jj) p2a[jj] = packbf_fast(p[2 * jj], p[2 * jj + 1]);
      }
      {
        float p[16];
#pragma unroll
        for (int g4 = 0; g4 < 4; ++g4) {
          float4 mv = *(const float4*)(MK + k0 + mt * 32 + g4 * 8 + q5 * 4);
          p[g4 * 4 + 0] = __builtin_amdgcn_exp2f(S1[g4 * 4 + 0] * C1 + mv.x);
          p[g4 * 4 + 1] = __builtin_amdgcn_exp2f(S1[g4 * 4 + 1] * C1 + mv.y);
          p[g4 * 4 + 2] = __builtin_amdgcn_exp2f(S1[g4 * 4 + 2] * C1 + mv.z);
          p[g4 * 4 + 3] = __builtin_amdgcn_exp2f(S1[g4 * 4 + 3] * C1 + mv.w);
        }
#pragma unroll
        for (int e = 0; e < 16; ++e) lsum1 += p[e];
#pragma unroll
        for (int jj = 0; jj < 8; ++jj) p2b[jj] = packbf_fast(p[2 * jj], p[2 * jj + 1]);
      }
#pragma unroll
      for (int kh = 0; kh < 2; ++kh) {
        int ks = mt * 2 + kh, gp = kh * 4;
        bf16x8 av0 = *(const bf16x8*)(VF + (0 * 4 + ks) * 1024 + lane * 16);
        bf16x8 av1 = *(const bf16x8*)(VF + (1 * 4 + ks) * 1024 + lane * 16);
        {
          unsigned o0 = p2a[gp + 0], o1 = p2a[gp + 1];
          unsigned o2 = p2a[gp + 2], o3 = p2a[gp + 3];
          unsigned t0 = __shfl_xor((int)o0, 32);
          unsigned t1 = __shfl_xor((int)o1, 32);
          unsigned t2 = __shfl_xor((int)o2, 32);
          unsigned t3 = __shfl_xor((int)o3, 32);
          uint4 fu;
          fu.x = q5 ? t2 : o0;
          fu.y = q5 ? t3 : o1;
          fu.z = q5 ? o2 : t0;
          fu.w = q5 ? o3 : t1;
          bf16x8 bfrag = __builtin_bit_cast(bf16x8, fu);
          O[0][0] = __builtin_amdgcn_mfma_f32_32x32x16_bf16(av0, bfrag, O[0][0], 0, 0, 0);
          O[0][1] = __builtin_amdgcn_mfma_f32_32x32x16_bf16(av1, bfrag, O[0][1], 0, 0, 0);
        }
        {
          unsigned o0 = p2b[gp + 0], o1 = p2b[gp + 1];
          unsigned o2 = p2b[gp + 2], o3 = p2b[gp + 3];
          unsigned t0 = __shfl_xor((int)o0, 32);
          unsigned t1 = __shfl_xor((int)o1, 32);
          unsigned t2 = __shfl_xor((int)o2, 32);
          unsigned t3 = __shfl_xor((int)o3, 32);
          uint4 fu;
          fu.x = q5 ? t2 : o0;
          fu.y = q5 ? t3 : o1;
          fu.z = q5 ? o2 : t0;
          fu.w = q5 ? o3 : t1;
          bf16x8 bfrag = __builtin_bit_cast(bf16x8, fu);
          O[1][0] = __builtin_amdgcn_mfma_f32_32x32x16_bf16(av0, bfrag, O[1][0], 0, 0, 0);
          O[1][1] = __builtin_amdgcn_mfma_f32_32x32x16_bf16(av1, bfrag, O[1][1], 0, 0, 0);
        }
      }
    }
    __syncthreads();  // drains kt+1 staging (overlapped by compute above)
  }

  // epilogue: normalize, transpose O^T via wave-private swizzled LDS scratch
  // (buffers free after the final barrier); two sequential passes (qh=0,1)
  // reuse the same 8KB scratch -- within-wave DS ordering is guaranteed.
  float* Ob = (float*)(lds + w * 8192);
  float lt0 = lsum0 + __shfl_xor(lsum0, 32);
  float lt1 = lsum1 + __shfl_xor(lsum1, 32);
  float rinv0 = 1.0f / lt0;
  float rinv1 = 1.0f / lt1;
#pragma unroll
  for (int qh = 0; qh < 2; ++qh) {
    float rinv = qh ? rinv1 : rinv0;
#pragma unroll
    for (int dt = 0; dt < 2; ++dt)
#pragma unroll
      for (int g4 = 0; g4 < 4; ++g4) {
        float4 val;
        val.x = O[qh][dt][g4 * 4 + 0] * rinv;
        val.y = O[qh][dt][g4 * 4 + 1] * rinv;
        val.z = O[qh][dt][g4 * 4 + 2] * rinv;
        val.w = O[qh][dt][g4 * 4 + 3] * rinv;
        int c = dt * 8 + g4 * 2 + q5;
        *(float4*)(Ob + l5 * 64 + (c ^ (l5 & 15)) * 4) = val;
      }
#pragma unroll
    for (int t = 0; t < 8; ++t) {
      int qr = t * 4 + (lane >> 4), cr = lane & 15;
      float4 vv = *(const float4*)(Ob + qr * 64 + (cr ^ (qr & 15)) * 4);
      int s = s0 + w * 64 + qh * 32 + qr;
      *(float4*)(out + (((size_t)(bi * 1024 + s)) << 10) + (h << 6) + (cr << 2)) = vv;
    }
  }
}

extern "C" void kernel_launch(void* const* d_in, const int* in_sizes, int n_in,
                              void* d_out, int out_size, void* d_ws, size_t ws_size,
                              hipStream_t stream) {
  (void)in_sizes; (void)n_in; (void)out_size; (void)ws_size;
  const float* hidden = (const float*)d_in[0];
  const float* mask = (const float*)d_in[1];
  const float* Wq = (const float*)d_in[2];
  const float* bq = (const float*)d_in[3];
  const float* Wk = (const float*)d_in[4];
  const float* bk = (const float*)d_in[5];
  const float* Wv = (const float*)d_in[6];
  const float* bv = (const float*)d_in[7];
  float* out = (float*)d_out;
  char* ws = (char*)d_ws;
  unsigned short* hbf = (unsigned short*)ws;                  // 16,777,216 B
  unsigned short* wt  = (unsigned short*)(ws + 16777216);     //  6,291,456 B
  unsigned short* qkv = (unsigned short*)(ws + 23068672);     // 33,554,432 B (q,k)
  unsigned short* vt  = (unsigned short*)(ws + 56623104);     // 16,777,216 B (v^T)

  k_prep<<<11264, 256, 0, stream>>>(hidden, hbf, Wq, Wk, Wv, wt);
  k_gemm<<<768, 256, 0, stream>>>(hbf, wt, bq, bk, bv, qkv, vt);
  k_attn<<<512, 256, 0, stream>>>(qkv, qkv + 8388608, vt, mask, out);
}

// Round 11
// 206.965 us; speedup vs baseline: 1.1549x; 1.0510x over previous
//
#include <hip/hip_runtime.h>

// BertSelfAttention on MI355X: bf16 MFMA QKV GEMM + flash-style attention.
// B=8 S=1024 HID=1024 NH=16 HD=64.
// R17: restore R14 (best-measured gemm 62.7us: 128x384 BK=32 fat-wave,
// 2 blocks/CU, grid 512 = 1 exact round; R16's 3-block/BK=32 regressed to
// 77.4us -> occupancy hypothesis dead both directions). One attn micro-fix:
// the P-redistribution needs only a pairwise lane<->lane+32 swap of (o2,o0),
// so pre-select va = q5 ? o0 : o2 and shuffle ONCE per word-pair instead of
// shuffling all four words and discarding half -> shfl (ds_bpermute) count
// halves, cutting LDS-pipe contention with K/V staging. Verified per-element
// against the original mapping:
//   fu.x = q5 ? ta : o0  (hi lane: lo.o2 ; lo lane: own o0)
//   fu.z = q5 ? o2 : ta  (hi lane: own o2 ; lo lane: hi.o0)
// k_prep identical to R14/R16.

typedef __bf16 bf16x8 __attribute__((ext_vector_type(8)));
typedef float f32x4 __attribute__((ext_vector_type(4)));
typedef float f32x16 __attribute__((ext_vector_type(16)));

__device__ __forceinline__ unsigned rne16(float x) {
  unsigned u = __builtin_bit_cast(unsigned, x);
  return (u + 0x7fffu + ((u >> 16) & 1u)) >> 16;
}
__device__ __forceinline__ unsigned packbf(float lo, float hi) {
  return rne16(lo) | (rne16(hi) << 16);
}
// fast pack (round-half-up) for softmax probabilities.
__device__ __forceinline__ unsigned packbf_fast(float lo, float hi) {
  unsigned ul = __builtin_bit_cast(unsigned, lo) + 0x8000u;
  unsigned uh = __builtin_bit_cast(unsigned, hi) + 0x8000u;
  return __builtin_amdgcn_perm(uh, ul, 0x07060302u);
}
// async global->LDS, 16B per lane; LDS dst is wave-uniform base + lane*16.
__device__ __forceinline__ void async16(void* l, const void* g) {
  __builtin_amdgcn_global_load_lds((const __attribute__((address_space(1))) void*)g,
                                   (__attribute__((address_space(3))) void*)l, 16, 0, 0);
}

// ---------------- fused: hidden fp32->bf16 (blocks 0..8191) + W transpose (8192..11263) ----
__global__ __launch_bounds__(256) void k_prep(const float* __restrict__ h,
                                              unsigned short* __restrict__ hbf,
                                              const float* __restrict__ Wq,
                                              const float* __restrict__ Wk,
                                              const float* __restrict__ Wv,
                                              unsigned short* __restrict__ wt) {
  __shared__ float t[32][33];
  int bid = blockIdx.x, tid = threadIdx.x;
  if (bid < 8192) {
    size_t i = (size_t)bid * 256 + tid;
    float4 v = ((const float4*)h)[i];
    uint2 r;
    r.x = packbf(v.x, v.y);
    r.y = packbf(v.z, v.w);
    ((uint2*)hbf)[i] = r;
  } else {
    int id = bid - 8192;           // 0..3071
    int which = id >> 10;
    int sub = id & 1023;
    int c0 = (sub & 31) * 32, k0 = (sub >> 5) * 32;
    const float* W = which == 0 ? Wq : (which == 1 ? Wk : Wv);
    int tx = tid & 31, ty = tid >> 5;
#pragma unroll
    for (int i = 0; i < 4; ++i) {
      int r = ty + i * 8;
      t[r][tx] = W[(size_t)(k0 + r) * 1024 + c0 + tx];
    }
    __syncthreads();
#pragma unroll
    for (int i = 0; i < 4; ++i) {
      int r = ty + i * 8;
      wt[((size_t)which * 1024 + c0 + r) * 1024 + k0 + tx] = (unsigned short)rne16(t[tx][r]);
    }
  }
}

// ---------------- QKV GEMM: [8192x1024] x [1024x3072]^T + bias, 128x384 tile, BK=32 ----------
// Double-buffered LDS, 32KB per buffer: A [128][32] (8KB, 8 subtiles of
// 16r x 32k = 1KB) at +0, B [384][32] (24KB, 24 subtiles) at +8192. Within
// each 1KB subtile byte offsets are XOR-swizzled (off ^= ((off>>9)&1)<<5);
// staging uses the inverse-swizzled global source, reads the swizzled lane
// offset -> conflict-free ds_read_b128 (both maps harness-proven). 4 waves,
// wave grid 2m x 2n, wave tile 64x192: per K-step 16 ds_reads feed 48 MFMA
// (ratio 3.0 vs 2.0 at 64x64 -> -33% LDS read traffic). Grid 512 = 2
// blocks/CU x 256 CU = one exact residency round. [R14-measured: 62.7us,
// FETCH 34MB, MfmaUtil 33%]
__global__ __launch_bounds__(256, 2) void k_gemm(const unsigned short* __restrict__ A,
                                                 const unsigned short* __restrict__ Bm,
                                                 const float* __restrict__ bq,
                                                 const float* __restrict__ bk,
                                                 const float* __restrict__ bv,
                                                 unsigned short* __restrict__ qkv,
                                                 unsigned short* __restrict__ vt) {
  __shared__ __align__(16) char lds[65536];
  const int tid = threadIdx.x;
  const int w = tid >> 6, lane = tid & 63;
  const int wm = w >> 1, wn = w & 1;  // wave tile 64 rows x 192 cols

  // bijective XCD swizzle: 512 blocks = 8 XCDs x 64; tn fastest within a
  // chunk so each XCD's L2 holds 8 A-panels (2MB) while B rotates.
  int orig = blockIdx.x;
  int wgid = (orig & 7) * 64 + (orig >> 3);
  int tm = wgid >> 3, tn = wgid & 7;
  int m0 = tm * 128, n0 = tn * 384;

  // staging map: linear LDS dest chunk o -> (row, k) source, inverse of the
  // read-side swizzle (same involution; BK=32 variant proven in R11).
  int ro[6], ke[6];
#pragma unroll
  for (int j = 0; j < 6; ++j) {
    int o = j * 4096 + tid * 16;
    int s = o >> 10, w10 = o & 1023;
    int lg = w10 ^ (((w10 >> 9) & 1) << 5);
    ro[j] = s * 16 + (lg >> 6);
    ke[j] = (lg & 63) >> 1;
  }
  auto stage = [&](int kt, char* buf) {
    const unsigned short* As = A + (size_t)m0 * 1024 + kt * 32;
    const unsigned short* Bs = Bm + (size_t)n0 * 1024 + kt * 32;
#pragma unroll
    for (int j = 0; j < 2; ++j)
      async16(buf + j * 4096 + tid * 16, As + (size_t)ro[j] * 1024 + ke[j]);
#pragma unroll
    for (int j = 0; j < 6; ++j)
      async16(buf + 8192 + j * 4096 + tid * 16, Bs + (size_t)ro[j] * 1024 + ke[j]);
  };

  // read-side per-lane swizzled offset within a 1KB subtile.
  const int lswz = (((lane & 15) << 6) | ((lane >> 4) << 4)) ^ ((lane & 8) << 2);

  f32x4 acc[4][12];
#pragma unroll
  for (int i = 0; i < 4; ++i)
#pragma unroll
    for (int j = 0; j < 12; ++j)
#pragma unroll
      for (int e = 0; e < 4; ++e) acc[i][j][e] = 0.f;

  auto compute = [&](const char* buf) {
    const char* abase = buf + lswz;
    const char* bbase = buf + 8192 + lswz;
    bf16x8 aF[4];
#pragma unroll
    for (int mt = 0; mt < 4; ++mt)
      aF[mt] = *(const bf16x8*)(abase + ((size_t)(wm * 4 + mt) << 10));
#pragma unroll
    for (int n = 0; n < 12; ++n) {
      bf16x8 bF = *(const bf16x8*)(bbase + ((size_t)(wn * 12 + n) << 10));
#pragma unroll
      for (int mt = 0; mt < 4; ++mt)
        acc[mt][n] =
            __builtin_amdgcn_mfma_f32_16x16x32_bf16(aF[mt], bF, acc[mt][n], 0, 0, 0);
    }
  };

  char* buf0 = lds;
  char* buf1 = lds + 32768;
  stage(0, buf0);
#pragma unroll 1
  for (int kt = 0; kt < 32; kt += 2) {
    __syncthreads();
    stage(kt + 1, buf1);
    compute(buf0);
    __syncthreads();
    if (kt + 2 < 32) stage(kt + 2, buf0);
    compute(buf1);
  }

  // epilogue. C fragment: col(n) = lane&15, row(s) = (lane>>4)*4 + e.
  // which is per-n-frag (wave-uniform: frags are 16-wide, boundaries 1024).
  const int b = m0 >> 10;
  const int r = lane & 15, qq = lane >> 4;
  const int sb = (m0 & 1023) + wm * 64 + qq * 4;
#pragma unroll
  for (int n = 0; n < 12; ++n) {
    int n_gf = n0 + wn * 192 + n * 16;
    int which = n_gf >> 10;
    int n_in = (n_gf & 1023) + r;
    if (which != 2) {
      // q / k: scattered 2B stores into [b][h][s][d] (proven path).
      const float* bp = which == 0 ? bq : bk;
      float bias = bp[n_in];
      unsigned short* dp = qkv + ((size_t)which << 23) + ((size_t)b << 20) +
                           ((size_t)(n_in >> 6) << 16) + (n_in & 63);
#pragma unroll
      for (int m = 0; m < 4; ++m)
#pragma unroll
        for (int e = 0; e < 4; ++e)
          dp[(size_t)(sb + m * 16 + e) << 6] = (unsigned short)rne16(acc[m][n][e] + bias);
    } else {
      // v: store V^T [b][h][d][s] directly — each lane owns 4 consecutive s
      // (e=0..3) at fixed d, packed as one 8B store.
      float bias = bv[n_in];
      unsigned short* dp = vt + ((size_t)b << 20) + ((size_t)n_in << 10) + sb;
#pragma unroll
      for (int m = 0; m < 4; ++m) {
        uint2 pk;
        pk.x = packbf(acc[m][n][0] + bias, acc[m][n][1] + bias);
        pk.y = packbf(acc[m][n][2] + bias, acc[m][n][3] + bias);
        *(uint2*)(dp + m * 16) = pk;
      }
    }
  }
}

// ---------------- attention: S^T = K*Q^T, softmax (no max-sub), O^T = V^T*P ----------------
// 512 blocks; block = (b,h, 256-qrow chunk); wave = 64 qrows (two 32-row Q
// fragments qh=0,1 SHARING each K/V LDS read). 64-key tiles, double-buffered
// K/V staging, one barrier per kt. XCD swizzle: b = blockIdx&7. 2 blocks/CU.
// R17: single-shuffle P-redistribution (pairwise swap, 2 shfl instead of 4).
__global__ __launch_bounds__(256, 2) void k_attn(const unsigned short* __restrict__ qg,
                                                 const unsigned short* __restrict__ kg,
                                                 const unsigned short* __restrict__ vtg,
                                                 const float* __restrict__ maskg,
                                                 float* __restrict__ out) {
  __shared__ __align__(16) char lds[36864];
  // buffers d=0,1 at d*16384: K 8KB (64 keys x 64 dims) + V^T 8KB (64 dims x
  // 64 keys). Mask table 4KB at +32768. Epilogue scratch reuses buffers.
  float* MK = (float*)(lds + 32768);
  int tid = threadIdx.x, w = tid >> 6, lane = tid & 63, l5 = lane & 31, q5 = lane >> 5;
  int idx = blockIdx.x;
  int bi = idx & 7;                   // batch == XCD (round-robin dispatch heuristic)
  int j = idx >> 3;                   // 0..63
  int h = j >> 2, qc = j & 3;
  int bh = bi * 16 + h, s0 = qc * 256;
  const unsigned short* qb = qg + ((size_t)bh << 16);
  const unsigned short* kb = kg + ((size_t)bh << 16);
  const unsigned short* vb = vtg + ((size_t)bh << 16);
  const float LG = 1.4426950408889634f;
  const float C1 = 0.125f * LG;

  {
    float4 mv = *(const float4*)(maskg + (size_t)bi * 1024 + tid * 4);
    mv.x *= LG; mv.y *= LG; mv.z *= LG; mv.w *= LG;
    *(float4*)(MK + tid * 4) = mv;
  }

  // stage K/V tile kt (64 keys at k0=kt*64) into buffer buf. Per wave: 2 K
  // chunks + 2 V chunks (4 waves cover 8+8 x 1KB). Per-lane identity
  // correspondence between write and read (harness-verified map).
  auto stageKV = [&](int kt, char* buf) {
    int k0 = kt * 64;
#pragma unroll
    for (int t = 0; t < 2; ++t) {
      int f = w * 2 + t;
      int mt = f >> 2, ds = f & 3;
      async16(buf + f * 1024, kb + (size_t)(k0 + mt * 32 + l5) * 64 + ds * 16 + q5 * 8);
      int dt = f >> 2, ks = f & 3;
      async16(buf + 8192 + f * 1024,
              vb + (size_t)(dt * 32 + l5) * 1024 + k0 + ks * 16 + q5 * 8);
    }
  };

  bf16x8 qfr[2][4];
#pragma unroll
  for (int qh = 0; qh < 2; ++qh)
#pragma unroll
    for (int ds = 0; ds < 4; ++ds)
      qfr[qh][ds] = *(const bf16x8*)(qb + (size_t)(s0 + w * 64 + qh * 32 + l5) * 64 +
                                     ds * 16 + q5 * 8);

  f32x16 O[2][2];
#pragma unroll
  for (int qh = 0; qh < 2; ++qh)
#pragma unroll
    for (int i = 0; i < 2; ++i)
#pragma unroll
      for (int e = 0; e < 16; ++e) O[qh][i][e] = 0.f;
  float lsum0 = 0.f, lsum1 = 0.f;

  stageKV(0, lds);
  __syncthreads();  // tile 0 landed (implicit vmcnt(0)), mask table visible

#pragma unroll 1
  for (int kt = 0; kt < 16; ++kt) {
    char* buf = lds + (kt & 1) * 16384;
    if (kt < 15) stageKV(kt + 1, lds + ((kt + 1) & 1) * 16384);
    int k0 = kt * 64;
    const char* KF = buf;
    const char* VF = buf + 8192;
#pragma unroll
    for (int mt = 0; mt < 2; ++mt) {
      f32x16 S0, S1;
#pragma unroll
      for (int e = 0; e < 16; ++e) { S0[e] = 0.f; S1[e] = 0.f; }
#pragma unroll
      for (int ds = 0; ds < 4; ++ds) {
        bf16x8 a = *(const bf16x8*)(KF + (mt * 4 + ds) * 1024 + lane * 16);
        S0 = __builtin_amdgcn_mfma_f32_32x32x16_bf16(a, qfr[0][ds], S0, 0, 0, 0);
        S1 = __builtin_amdgcn_mfma_f32_32x32x16_bf16(a, qfr[1][ds], S1, 0, 0, 0);
      }
      unsigned p2a[8], p2b[8];
      {
        float p[16];
#pragma unroll
        for (int g4 = 0; g4 < 4; ++g4) {
          float4 mv = *(const float4*)(MK + k0 + mt * 32 + g4 * 8 + q5 * 4);
          p[g4 * 4 + 0] = __builtin_amdgcn_exp2f(S0[g4 * 4 + 0] * C1 + mv.x);
          p[g4 * 4 + 1] = __builtin_amdgcn_exp2f(S0[g4 * 4 + 1] * C1 + mv.y);
          p[g4 * 4 + 2] = __builtin_amdgcn_exp2f(S0[g4 * 4 + 2] * C1 + mv.z);
          p[g4 * 4 + 3] = __builtin_amdgcn_exp2f(S0[g4 * 4 + 3] * C1 + mv.w);
        }
#pragma unroll
        for (int e = 0; e < 16; ++e) lsum0 += p[e];
#pragma unroll
        for (int jj = 0; jj < 8; ++jj) p2a[jj] = packbf_fast(p[2 * jj], p[2 * jj + 1]);
      }
      {
        float p[16];
#pragma unroll
        for (int g4 = 0; g4 < 4; ++g4) {
          float4 mv = *(const float4*)(MK + k0 + mt * 32 + g4 * 8 + q5 * 4);
          p[g4 * 4 + 0] = __builtin_amdgcn_exp2f(S1[g4 * 4 + 0] * C1 + mv.x);
          p[g4 * 4 + 1] = __builtin_amdgcn_exp2f(S1[g4 * 4 + 1] * C1 + mv.y);
          p[g4 * 4 + 2] = __builtin_amdgcn_exp2f(S1[g4 * 4 + 2] * C1 + mv.z);
          p[g4 * 4 + 3] = __builtin_amdgcn_exp2f(S1[g4 * 4 + 3] * C1 + mv.w);
        }
#pragma unroll
        for (int e = 0; e < 16; ++e) lsum1 += p[e];
#pragma unroll
        for (int jj = 0; jj < 8; ++jj) p2b[jj] = packbf_fast(p[2 * jj], p[2 * jj + 1]);
      }
#pragma unroll
      for (int kh = 0; kh < 2; ++kh) {
        int ks = mt * 2 + kh, gp = kh * 4;
        bf16x8 av0 = *(const bf16x8*)(VF + (0 * 4 + ks) * 1024 + lane * 16);
        bf16x8 av1 = *(const bf16x8*)(VF + (1 * 4 + ks) * 1024 + lane * 16);
        {
          unsigned o0 = p2a[gp + 0], o1 = p2a[gp + 1];
          unsigned o2 = p2a[gp + 2], o3 = p2a[gp + 3];
          // pairwise swap: hi lane sends o0/o1, lo lane sends o2/o3.
          unsigned va = q5 ? o0 : o2;
          unsigned vb2 = q5 ? o1 : o3;
          unsigned ta = __shfl_xor((int)va, 32);
          unsigned tb = __shfl_xor((int)vb2, 32);
          uint4 fu;
          fu.x = q5 ? ta : o0;
          fu.y = q5 ? tb : o1;
          fu.z = q5 ? o2 : ta;
          fu.w = q5 ? o3 : tb;
          bf16x8 bfrag = __builtin_bit_cast(bf16x8, fu);
          O[0][0] = __builtin_amdgcn_mfma_f32_32x32x16_bf16(av0, bfrag, O[0][0], 0, 0, 0);
          O[0][1] = __builtin_amdgcn_mfma_f32_32x32x16_bf16(av1, bfrag, O[0][1], 0, 0, 0);
        }
        {
          unsigned o0 = p2b[gp + 0], o1 = p2b[gp + 1];
          unsigned o2 = p2b[gp + 2], o3 = p2b[gp + 3];
          unsigned va = q5 ? o0 : o2;
          unsigned vb2 = q5 ? o1 : o3;
          unsigned ta = __shfl_xor((int)va, 32);
          unsigned tb = __shfl_xor((int)vb2, 32);
          uint4 fu;
          fu.x = q5 ? ta : o0;
          fu.y = q5 ? tb : o1;
          fu.z = q5 ? o2 : ta;
          fu.w = q5 ? o3 : tb;
          bf16x8 bfrag = __builtin_bit_cast(bf16x8, fu);
          O[1][0] = __builtin_amdgcn_mfma_f32_32x32x16_bf16(av0, bfrag, O[1][0], 0, 0, 0);
          O[1][1] = __builtin_amdgcn_mfma_f32_32x32x16_bf16(av1, bfrag, O[1][1], 0, 0, 0);
        }
      }
    }
    __syncthreads();  // drains kt+1 staging (overlapped by compute above)
  }

  // epilogue: normalize, transpose O^T via wave-private swizzled LDS scratch
  // (buffers free after the final barrier); two sequential passes (qh=0,1)
  // reuse the same 8KB scratch -- within-wave DS ordering is guaranteed.
  float* Ob = (float*)(lds + w * 8192);
  float lt0 = lsum0 + __shfl_xor(lsum0, 32);
  float lt1 = lsum1 + __shfl_xor(lsum1, 32);
  float rinv0 = 1.0f / lt0;
  float rinv1 = 1.0f / lt1;
#pragma unroll
  for (int qh = 0; qh < 2; ++qh) {
    float rinv = qh ? rinv1 : rinv0;
#pragma unroll
    for (int dt = 0; dt < 2; ++dt)
#pragma unroll
      for (int g4 = 0; g4 < 4; ++g4) {
        float4 val;
        val.x = O[qh][dt][g4 * 4 + 0] * rinv;
        val.y = O[qh][dt][g4 * 4 + 1] * rinv;
        val.z = O[qh][dt][g4 * 4 + 2] * rinv;
        val.w = O[qh][dt][g4 * 4 + 3] * rinv;
        int c = dt * 8 + g4 * 2 + q5;
        *(float4*)(Ob + l5 * 64 + (c ^ (l5 & 15)) * 4) = val;
      }
#pragma unroll
    for (int t = 0; t < 8; ++t) {
      int qr = t * 4 + (lane >> 4), cr = lane & 15;
      float4 vv = *(const float4*)(Ob + qr * 64 + (cr ^ (qr & 15)) * 4);
      int s = s0 + w * 64 + qh * 32 + qr;
      *(float4*)(out + (((size_t)(bi * 1024 + s)) << 10) + (h << 6) + (cr << 2)) = vv;
    }
  }
}

extern "C" void kernel_launch(void* const* d_in, const int* in_sizes, int n_in,
                              void* d_out, int out_size, void* d_ws, size_t ws_size,
                              hipStream_t stream) {
  (void)in_sizes; (void)n_in; (void)out_size; (void)ws_size;
  const float* hidden = (const float*)d_in[0];
  const float* mask = (const float*)d_in[1];
  const float* Wq = (const float*)d_in[2];
  const float* bq = (const float*)d_in[3];
  const float* Wk = (const float*)d_in[4];
  const float* bk = (const float*)d_in[5];
  const float* Wv = (const float*)d_in[6];
  const float* bv = (const float*)d_in[7];
  float* out = (float*)d_out;
  char* ws = (char*)d_ws;
  unsigned short* hbf = (unsigned short*)ws;                  // 16,777,216 B
  unsigned short* wt  = (unsigned short*)(ws + 16777216);     //  6,291,456 B
  unsigned short* qkv = (unsigned short*)(ws + 23068672);     // 33,554,432 B (q,k)
  unsigned short* vt  = (unsigned short*)(ws + 56623104);     // 16,777,216 B (v^T)

  k_prep<<<11264, 256, 0, stream>>>(hidden, hbf, Wq, Wk, Wv, wt);
  k_gemm<<<512, 256, 0, stream>>>(hbf, wt, bq, bk, bv, qkv, vt);
  k_attn<<<512, 256, 0, stream>>>(qkv, qkv + 8388608, vt, mask, out);
}

// Round 12
// 203.554 us; speedup vs baseline: 1.1742x; 1.0168x over previous
//
#include <hip/hip_runtime.h>

// BertSelfAttention on MI355X: bf16 MFMA QKV GEMM + flash-style attention.
// B=8 S=1024 HID=1024 NH=16 HD=64.
// R18: attn KVBLK 64->128 (halve barrier/drain count). R12/R13/R17 showed
// attn responds to traffic/overhead cuts (qh-reuse +3us, shuffle-halving
// +2us), not latency restructuring. The per-kt __syncthreads (vmcnt(0)+
// barrier across 4 waves) count halves 16->8 by doubling the K/V tile;
// staging/read maps are the harness-proven R10 128-key maps verbatim; LDS
// 2x32KB + 4KB mask = 68KB -> still 2 blocks/CU. Per-kt: 32 ds_reads feed
// 32 MFMA-pairs between barriers (best MFMA-per-barrier attn config yet).
// Traffic, MFMA count, softmax VALU identical to R17.
// k_prep / k_gemm byte-identical to R17 (gemm 62.6us canary:
// 128x384 BK=32 fat-wave, 2 blocks/CU, grid 512 = 1 exact round).

typedef __bf16 bf16x8 __attribute__((ext_vector_type(8)));
typedef float f32x4 __attribute__((ext_vector_type(4)));
typedef float f32x16 __attribute__((ext_vector_type(16)));

__device__ __forceinline__ unsigned rne16(float x) {
  unsigned u = __builtin_bit_cast(unsigned, x);
  return (u + 0x7fffu + ((u >> 16) & 1u)) >> 16;
}
__device__ __forceinline__ unsigned packbf(float lo, float hi) {
  return rne16(lo) | (rne16(hi) << 16);
}
// fast pack (round-half-up) for softmax probabilities.
__device__ __forceinline__ unsigned packbf_fast(float lo, float hi) {
  unsigned ul = __builtin_bit_cast(unsigned, lo) + 0x8000u;
  unsigned uh = __builtin_bit_cast(unsigned, hi) + 0x8000u;
  return __builtin_amdgcn_perm(uh, ul, 0x07060302u);
}
// async global->LDS, 16B per lane; LDS dst is wave-uniform base + lane*16.
__device__ __forceinline__ void async16(void* l, const void* g) {
  __builtin_amdgcn_global_load_lds((const __attribute__((address_space(1))) void*)g,
                                   (__attribute__((address_space(3))) void*)l, 16, 0, 0);
}

// ---------------- fused: hidden fp32->bf16 (blocks 0..8191) + W transpose (8192..11263) ----
__global__ __launch_bounds__(256) void k_prep(const float* __restrict__ h,
                                              unsigned short* __restrict__ hbf,
                                              const float* __restrict__ Wq,
                                              const float* __restrict__ Wk,
                                              const float* __restrict__ Wv,
                                              unsigned short* __restrict__ wt) {
  __shared__ float t[32][33];
  int bid = blockIdx.x, tid = threadIdx.x;
  if (bid < 8192) {
    size_t i = (size_t)bid * 256 + tid;
    float4 v = ((const float4*)h)[i];
    uint2 r;
    r.x = packbf(v.x, v.y);
    r.y = packbf(v.z, v.w);
    ((uint2*)hbf)[i] = r;
  } else {
    int id = bid - 8192;           // 0..3071
    int which = id >> 10;
    int sub = id & 1023;
    int c0 = (sub & 31) * 32, k0 = (sub >> 5) * 32;
    const float* W = which == 0 ? Wq : (which == 1 ? Wk : Wv);
    int tx = tid & 31, ty = tid >> 5;
#pragma unroll
    for (int i = 0; i < 4; ++i) {
      int r = ty + i * 8;
      t[r][tx] = W[(size_t)(k0 + r) * 1024 + c0 + tx];
    }
    __syncthreads();
#pragma unroll
    for (int i = 0; i < 4; ++i) {
      int r = ty + i * 8;
      wt[((size_t)which * 1024 + c0 + r) * 1024 + k0 + tx] = (unsigned short)rne16(t[tx][r]);
    }
  }
}

// ---------------- QKV GEMM: [8192x1024] x [1024x3072]^T + bias, 128x384 tile, BK=32 ----------
// Double-buffered LDS, 32KB per buffer: A [128][32] (8KB, 8 subtiles of
// 16r x 32k = 1KB) at +0, B [384][32] (24KB, 24 subtiles) at +8192. Within
// each 1KB subtile byte offsets are XOR-swizzled (off ^= ((off>>9)&1)<<5);
// staging uses the inverse-swizzled global source, reads the swizzled lane
// offset -> conflict-free ds_read_b128 (both maps harness-proven). 4 waves,
// wave grid 2m x 2n, wave tile 64x192: per K-step 16 ds_reads feed 48 MFMA.
// Grid 512 = 2 blocks/CU x 256 CU = one exact residency round.
// [R14/R17-measured: 62.6us, FETCH 34MB, MfmaUtil 33%]
__global__ __launch_bounds__(256, 2) void k_gemm(const unsigned short* __restrict__ A,
                                                 const unsigned short* __restrict__ Bm,
                                                 const float* __restrict__ bq,
                                                 const float* __restrict__ bk,
                                                 const float* __restrict__ bv,
                                                 unsigned short* __restrict__ qkv,
                                                 unsigned short* __restrict__ vt) {
  __shared__ __align__(16) char lds[65536];
  const int tid = threadIdx.x;
  const int w = tid >> 6, lane = tid & 63;
  const int wm = w >> 1, wn = w & 1;  // wave tile 64 rows x 192 cols

  // bijective XCD swizzle: 512 blocks = 8 XCDs x 64; tn fastest within a
  // chunk so each XCD's L2 holds 8 A-panels (2MB) while B rotates.
  int orig = blockIdx.x;
  int wgid = (orig & 7) * 64 + (orig >> 3);
  int tm = wgid >> 3, tn = wgid & 7;
  int m0 = tm * 128, n0 = tn * 384;

  // staging map: linear LDS dest chunk o -> (row, k) source, inverse of the
  // read-side swizzle (same involution; BK=32 variant proven in R11).
  int ro[6], ke[6];
#pragma unroll
  for (int j = 0; j < 6; ++j) {
    int o = j * 4096 + tid * 16;
    int s = o >> 10, w10 = o & 1023;
    int lg = w10 ^ (((w10 >> 9) & 1) << 5);
    ro[j] = s * 16 + (lg >> 6);
    ke[j] = (lg & 63) >> 1;
  }
  auto stage = [&](int kt, char* buf) {
    const unsigned short* As = A + (size_t)m0 * 1024 + kt * 32;
    const unsigned short* Bs = Bm + (size_t)n0 * 1024 + kt * 32;
#pragma unroll
    for (int j = 0; j < 2; ++j)
      async16(buf + j * 4096 + tid * 16, As + (size_t)ro[j] * 1024 + ke[j]);
#pragma unroll
    for (int j = 0; j < 6; ++j)
      async16(buf + 8192 + j * 4096 + tid * 16, Bs + (size_t)ro[j] * 1024 + ke[j]);
  };

  // read-side per-lane swizzled offset within a 1KB subtile.
  const int lswz = (((lane & 15) << 6) | ((lane >> 4) << 4)) ^ ((lane & 8) << 2);

  f32x4 acc[4][12];
#pragma unroll
  for (int i = 0; i < 4; ++i)
#pragma unroll
    for (int j = 0; j < 12; ++j)
#pragma unroll
      for (int e = 0; e < 4; ++e) acc[i][j][e] = 0.f;

  auto compute = [&](const char* buf) {
    const char* abase = buf + lswz;
    const char* bbase = buf + 8192 + lswz;
    bf16x8 aF[4];
#pragma unroll
    for (int mt = 0; mt < 4; ++mt)
      aF[mt] = *(const bf16x8*)(abase + ((size_t)(wm * 4 + mt) << 10));
#pragma unroll
    for (int n = 0; n < 12; ++n) {
      bf16x8 bF = *(const bf16x8*)(bbase + ((size_t)(wn * 12 + n) << 10));
#pragma unroll
      for (int mt = 0; mt < 4; ++mt)
        acc[mt][n] =
            __builtin_amdgcn_mfma_f32_16x16x32_bf16(aF[mt], bF, acc[mt][n], 0, 0, 0);
    }
  };

  char* buf0 = lds;
  char* buf1 = lds + 32768;
  stage(0, buf0);
#pragma unroll 1
  for (int kt = 0; kt < 32; kt += 2) {
    __syncthreads();
    stage(kt + 1, buf1);
    compute(buf0);
    __syncthreads();
    if (kt + 2 < 32) stage(kt + 2, buf0);
    compute(buf1);
  }

  // epilogue. C fragment: col(n) = lane&15, row(s) = (lane>>4)*4 + e.
  // which is per-n-frag (wave-uniform: frags are 16-wide, boundaries 1024).
  const int b = m0 >> 10;
  const int r = lane & 15, qq = lane >> 4;
  const int sb = (m0 & 1023) + wm * 64 + qq * 4;
#pragma unroll
  for (int n = 0; n < 12; ++n) {
    int n_gf = n0 + wn * 192 + n * 16;
    int which = n_gf >> 10;
    int n_in = (n_gf & 1023) + r;
    if (which != 2) {
      // q / k: scattered 2B stores into [b][h][s][d] (proven path).
      const float* bp = which == 0 ? bq : bk;
      float bias = bp[n_in];
      unsigned short* dp = qkv + ((size_t)which << 23) + ((size_t)b << 20) +
                           ((size_t)(n_in >> 6) << 16) + (n_in & 63);
#pragma unroll
      for (int m = 0; m < 4; ++m)
#pragma unroll
        for (int e = 0; e < 4; ++e)
          dp[(size_t)(sb + m * 16 + e) << 6] = (unsigned short)rne16(acc[m][n][e] + bias);
    } else {
      // v: store V^T [b][h][d][s] directly — each lane owns 4 consecutive s
      // (e=0..3) at fixed d, packed as one 8B store.
      float bias = bv[n_in];
      unsigned short* dp = vt + ((size_t)b << 20) + ((size_t)n_in << 10) + sb;
#pragma unroll
      for (int m = 0; m < 4; ++m) {
        uint2 pk;
        pk.x = packbf(acc[m][n][0] + bias, acc[m][n][1] + bias);
        pk.y = packbf(acc[m][n][2] + bias, acc[m][n][3] + bias);
        *(uint2*)(dp + m * 16) = pk;
      }
    }
  }
}

// ---------------- attention: S^T = K*Q^T, softmax (no max-sub), O^T = V^T*P ----------------
// 512 blocks; block = (b,h, 256-qrow chunk); wave = 64 qrows (two 32-row Q
// fragments qh=0,1 SHARING each K/V LDS read). R18: 128-key tiles (KVBLK=128,
// R10's proven staging/read maps), double-buffered, ONE barrier per kt ->
// 8 barrier+vmcnt(0) drains instead of 16. XCD swizzle: b = blockIdx&7.
// LDS 2x32KB + 4KB mask = 68KB -> 2 blocks/CU.
__global__ __launch_bounds__(256, 2) void k_attn(const unsigned short* __restrict__ qg,
                                                 const unsigned short* __restrict__ kg,
                                                 const unsigned short* __restrict__ vtg,
                                                 const float* __restrict__ maskg,
                                                 float* __restrict__ out) {
  __shared__ __align__(16) char lds[69632];
  // buffers d=0,1 at d*32768: K 16KB (128 keys x 64 dims, 16 x 1KB chunks) +
  // V^T 16KB (64 dims x 128 keys) at +16384. Mask table 4KB at +65536.
  // Epilogue scratch reuses buffer 0 (wave-private 8KB each).
  float* MK = (float*)(lds + 65536);
  int tid = threadIdx.x, w = tid >> 6, lane = tid & 63, l5 = lane & 31, q5 = lane >> 5;
  int idx = blockIdx.x;
  int bi = idx & 7;                   // batch == XCD (round-robin dispatch heuristic)
  int j = idx >> 3;                   // 0..63
  int h = j >> 2, qc = j & 3;
  int bh = bi * 16 + h, s0 = qc * 256;
  const unsigned short* qb = qg + ((size_t)bh << 16);
  const unsigned short* kb = kg + ((size_t)bh << 16);
  const unsigned short* vb = vtg + ((size_t)bh << 16);
  const float LG = 1.4426950408889634f;
  const float C1 = 0.125f * LG;

  {
    float4 mv = *(const float4*)(maskg + (size_t)bi * 1024 + tid * 4);
    mv.x *= LG; mv.y *= LG; mv.z *= LG; mv.w *= LG;
    *(float4*)(MK + tid * 4) = mv;
  }

  // stage K/V tile kt (128 keys at k0=kt*128) into buffer buf. Per wave:
  // 4 K chunks + 4 V chunks (4 waves cover 16+16 x 1KB). Maps are R10's
  // harness-proven 128-key maps verbatim.
  auto stageKV = [&](int kt, char* buf) {
    int k0 = kt * 128;
#pragma unroll
    for (int t = 0; t < 4; ++t) {
      int f = w * 4 + t;
      int mt = f >> 2, ds = f & 3;
      async16(buf + f * 1024, kb + (size_t)(k0 + mt * 32 + l5) * 64 + ds * 16 + q5 * 8);
      int dt = f >> 3, ks = f & 7;
      async16(buf + 16384 + f * 1024,
              vb + (size_t)(dt * 32 + l5) * 1024 + k0 + ks * 16 + q5 * 8);
    }
  };

  bf16x8 qfr[2][4];
#pragma unroll
  for (int qh = 0; qh < 2; ++qh)
#pragma unroll
    for (int ds = 0; ds < 4; ++ds)
      qfr[qh][ds] = *(const bf16x8*)(qb + (size_t)(s0 + w * 64 + qh * 32 + l5) * 64 +
                                     ds * 16 + q5 * 8);

  f32x16 O[2][2];
#pragma unroll
  for (int qh = 0; qh < 2; ++qh)
#pragma unroll
    for (int i = 0; i < 2; ++i)
#pragma unroll
      for (int e = 0; e < 16; ++e) O[qh][i][e] = 0.f;
  float lsum0 = 0.f, lsum1 = 0.f;

  stageKV(0, lds);
  __syncthreads();  // tile 0 landed (implicit vmcnt(0)), mask table visible

#pragma unroll 1
  for (int kt = 0; kt < 8; ++kt) {
    char* buf = lds + (kt & 1) * 32768;
    if (kt < 7) stageKV(kt + 1, lds + ((kt + 1) & 1) * 32768);
    int k0 = kt * 128;
    const char* KF = buf;
    const char* VF = buf + 16384;
#pragma unroll
    for (int mt = 0; mt < 4; ++mt) {
      f32x16 S0, S1;
#pragma unroll
      for (int e = 0; e < 16; ++e) { S0[e] = 0.f; S1[e] = 0.f; }
#pragma unroll
      for (int ds = 0; ds < 4; ++ds) {
        bf16x8 a = *(const bf16x8*)(KF + (mt * 4 + ds) * 1024 + lane * 16);
        S0 = __builtin_amdgcn_mfma_f32_32x32x16_bf16(a, qfr[0][ds], S0, 0, 0, 0);
        S1 = __builtin_amdgcn_mfma_f32_32x32x16_bf16(a, qfr[1][ds], S1, 0, 0, 0);
      }
      unsigned p2a[8], p2b[8];
      {
        float p[16];
#pragma unroll
        for (int g4 = 0; g4 < 4; ++g4) {
          float4 mv = *(const float4*)(MK + k0 + mt * 32 + g4 * 8 + q5 * 4);
          p[g4 * 4 + 0] = __builtin_amdgcn_exp2f(S0[g4 * 4 + 0] * C1 + mv.x);
          p[g4 * 4 + 1] = __builtin_amdgcn_exp2f(S0[g4 * 4 + 1] * C1 + mv.y);
          p[g4 * 4 + 2] = __builtin_amdgcn_exp2f(S0[g4 * 4 + 2] * C1 + mv.z);
          p[g4 * 4 + 3] = __builtin_amdgcn_exp2f(S0[g4 * 4 + 3] * C1 + mv.w);
        }
#pragma unroll
        for (int e = 0; e < 16; ++e) lsum0 += p[e];
#pragma unroll
        for (int jj = 0; jj < 8; ++jj) p2a[jj] = packbf_fast(p[2 * jj], p[2 * jj + 1]);
      }
      {
        float p[16];
#pragma unroll
        for (int g4 = 0; g4 < 4; ++g4) {
          float4 mv = *(const float4*)(MK + k0 + mt * 32 + g4 * 8 + q5 * 4);
          p[g4 * 4 + 0] = __builtin_amdgcn_exp2f(S1[g4 * 4 + 0] * C1 + mv.x);
          p[g4 * 4 + 1] = __builtin_amdgcn_exp2f(S1[g4 * 4 + 1] * C1 + mv.y);
          p[g4 * 4 + 2] = __builtin_amdgcn_exp2f(S1[g4 * 4 + 2] * C1 + mv.z);
          p[g4 * 4 + 3] = __builtin_amdgcn_exp2f(S1[g4 * 4 + 3] * C1 + mv.w);
        }
#pragma unroll
        for (int e = 0; e < 16; ++e) lsum1 += p[e];
#pragma unroll
        for (int jj = 0; jj < 8; ++jj) p2b[jj] = packbf_fast(p[2 * jj], p[2 * jj + 1]);
      }
#pragma unroll
      for (int kh = 0; kh < 2; ++kh) {
        int ks = mt * 2 + kh, gp = kh * 4;
        bf16x8 av0 = *(const bf16x8*)(VF + (0 * 8 + ks) * 1024 + lane * 16);
        bf16x8 av1 = *(const bf16x8*)(VF + (1 * 8 + ks) * 1024 + lane * 16);
        {
          unsigned o0 = p2a[gp + 0], o1 = p2a[gp + 1];
          unsigned o2 = p2a[gp + 2], o3 = p2a[gp + 3];
          // pairwise swap: hi lane sends o0/o1, lo lane sends o2/o3.
          unsigned va = q5 ? o0 : o2;
          unsigned vb2 = q5 ? o1 : o3;
          unsigned ta = __shfl_xor((int)va, 32);
          unsigned tb = __shfl_xor((int)vb2, 32);
          uint4 fu;
          fu.x = q5 ? ta : o0;
          fu.y = q5 ? tb : o1;
          fu.z = q5 ? o2 : ta;
          fu.w = q5 ? o3 : tb;
          bf16x8 bfrag = __builtin_bit_cast(bf16x8, fu);
          O[0][0] = __builtin_amdgcn_mfma_f32_32x32x16_bf16(av0, bfrag, O[0][0], 0, 0, 0);
          O[0][1] = __builtin_amdgcn_mfma_f32_32x32x16_bf16(av1, bfrag, O[0][1], 0, 0, 0);
        }
        {
          unsigned o0 = p2b[gp + 0], o1 = p2b[gp + 1];
          unsigned o2 = p2b[gp + 2], o3 = p2b[gp + 3];
          unsigned va = q5 ? o0 : o2;
          unsigned vb2 = q5 ? o1 : o3;
          unsigned ta = __shfl_xor((int)va, 32);
          unsigned tb = __shfl_xor((int)vb2, 32);
          uint4 fu;
          fu.x = q5 ? ta : o0;
          fu.y = q5 ? tb : o1;
          fu.z = q5 ? o2 : ta;
          fu.w = q5 ? o3 : tb;
          bf16x8 bfrag = __builtin_bit_cast(bf16x8, fu);
          O[1][0] = __builtin_amdgcn_mfma_f32_32x32x16_bf16(av0, bfrag, O[1][0], 0, 0, 0);
          O[1][1] = __builtin_amdgcn_mfma_f32_32x32x16_bf16(av1, bfrag, O[1][1], 0, 0, 0);
        }
      }
    }
    __syncthreads();  // drains kt+1 staging (overlapped by compute above)
  }

  // epilogue: normalize, transpose O^T via wave-private swizzled LDS scratch
  // (buffer 0 free after the final barrier); two sequential passes (qh=0,1)
  // reuse the same 8KB scratch -- within-wave DS ordering is guaranteed.
  float* Ob = (float*)(lds + w * 8192);
  float lt0 = lsum0 + __shfl_xor(lsum0, 32);
  float lt1 = lsum1 + __shfl_xor(lsum1, 32);
  float rinv0 = 1.0f / lt0;
  float rinv1 = 1.0f / lt1;
#pragma unroll
  for (int qh = 0; qh < 2; ++qh) {
    float rinv = qh ? rinv1 : rinv0;
#pragma unroll
    for (int dt = 0; dt < 2; ++dt)
#pragma unroll
      for (int g4 = 0; g4 < 4; ++g4) {
        float4 val;
        val.x = O[qh][dt][g4 * 4 + 0] * rinv;
        val.y = O[qh][dt][g4 * 4 + 1] * rinv;
        val.z = O[qh][dt][g4 * 4 + 2] * rinv;
        val.w = O[qh][dt][g4 * 4 + 3] * rinv;
        int c = dt * 8 + g4 * 2 + q5;
        *(float4*)(Ob + l5 * 64 + (c ^ (l5 & 15)) * 4) = val;
      }
#pragma unroll
    for (int t = 0; t < 8; ++t) {
      int qr = t * 4 + (lane >> 4), cr = lane & 15;
      float4 vv = *(const float4*)(Ob + qr * 64 + (cr ^ (qr & 15)) * 4);
      int s = s0 + w * 64 + qh * 32 + qr;
      *(float4*)(out + (((size_t)(bi * 1024 + s)) << 10) + (h << 6) + (cr << 2)) = vv;
    }
  }
}

extern "C" void kernel_launch(void* const* d_in, const int* in_sizes, int n_in,
                              void* d_out, int out_size, void* d_ws, size_t ws_size,
                              hipStream_t stream) {
  (void)in_sizes; (void)n_in; (void)out_size; (void)ws_size;
  const float* hidden = (const float*)d_in[0];
  const float* mask = (const float*)d_in[1];
  const float* Wq = (const float*)d_in[2];
  const float* bq = (const float*)d_in[3];
  const float* Wk = (const float*)d_in[4];
  const float* bk = (const float*)d_in[5];
  const float* Wv = (const float*)d_in[6];
  const float* bv = (const float*)d_in[7];
  float* out = (float*)d_out;
  char* ws = (char*)d_ws;
  unsigned short* hbf = (unsigned short*)ws;                  // 16,777,216 B
  unsigned short* wt  = (unsigned short*)(ws + 16777216);     //  6,291,456 B
  unsigned short* qkv = (unsigned short*)(ws + 23068672);     // 33,554,432 B (q,k)
  unsigned short* vt  = (unsigned short*)(ws + 56623104);     // 16,777,216 B (v^T)

  k_prep<<<11264, 256, 0, stream>>>(hidden, hbf, Wq, Wk, Wv, wt);
  k_gemm<<<512, 256, 0, stream>>>(hbf, wt, bq, bk, bv, qkv, vt);
  k_attn<<<512, 256, 0, stream>>>(qkv, qkv + 8388608, vt, mask, out);
}